// Round 4
// baseline (125.381 us; speedup 1.0000x reference)
//
#include <hip/hip_runtime.h>
#include <hip/hip_bf16.h>

#define N_NODES 50000
#define N_EDGES 500000
#define IN_FEATS 96
#define OUT_FEATS 128
#define N_ETYPES 4
#define KCAT (N_ETYPES * IN_FEATS)  // 384

typedef __attribute__((ext_vector_type(8))) short short8;
typedef __attribute__((ext_vector_type(4))) short short4v;
typedef __attribute__((ext_vector_type(4))) float f32x4;

static __device__ inline short f2bf_bits(float f) {
    __hip_bfloat16 h = __float2bfloat16(f);
    return *reinterpret_cast<short*>(&h);
}
static __device__ inline unsigned pack2bf(float lo, float hi) {
    unsigned l = (unsigned short)f2bf_bits(lo);
    unsigned h = (unsigned short)f2bf_bits(hi);
    return l | (h << 16);
}

// ---------------------------------------------------------------------------
// Zero the degree array (replaces slow rocclr fillBuffer: 41us -> ~2us)
// ---------------------------------------------------------------------------
__global__ __launch_bounds__(256) void k_zero(int* __restrict__ deg) {
    int g = blockIdx.x * 256 + threadIdx.x;
    if (g < N_NODES) deg[g] = 0;
}

// feat f32 [N,96] -> packed bf16 pairs u32 [N,48]
__global__ __launch_bounds__(256) void k_cvt(const float2* __restrict__ feat2,
                                             unsigned* __restrict__ featb) {
    int g = blockIdx.x * 256 + threadIdx.x;
    if (g < N_NODES * 48) {
        float2 v = feat2[g];
        featb[g] = pack2bf(v.x, v.y);
    }
}

// ---------------------------------------------------------------------------
// Sort-by-dst machinery: hist -> scan (2-level) -> bin (packed src|et)
// ---------------------------------------------------------------------------
__global__ __launch_bounds__(256) void k_hist(const int* __restrict__ dst, int* __restrict__ deg) {
    int e = blockIdx.x * 256 + threadIdx.x;
    if (e < N_EDGES) atomicAdd(&deg[dst[e]], 1);
}

__global__ __launch_bounds__(256) void k_scan1(const int* __restrict__ in, int n,
                                               int* __restrict__ out, int* __restrict__ bsum) {
    int g = blockIdx.x * 256 + threadIdx.x;
    int lane = threadIdx.x & 63, wave = threadIdx.x >> 6;
    int v = (g < n) ? in[g] : 0;
    int orig = v;
    for (int off = 1; off < 64; off <<= 1) {
        int u = __shfl_up(v, off);
        if (lane >= off) v += u;
    }
    __shared__ int wsum[4];
    if (lane == 63) wsum[wave] = v;
    __syncthreads();
    if (threadIdx.x == 0) {
        int s = 0;
        for (int w = 0; w < 4; ++w) { int t = wsum[w]; wsum[w] = s; s += t; }
        bsum[blockIdx.x] = s;
    }
    __syncthreads();
    int excl = v - orig + wsum[wave];
    if (g < n) out[g] = excl;
}

__global__ __launch_bounds__(256) void k_scan3(int* __restrict__ pos, const int* __restrict__ bscan,
                                               int* __restrict__ cursor, int n) {
    int g = blockIdx.x * 256 + threadIdx.x;
    if (g < n) {
        int p = pos[g] + bscan[blockIdx.x];
        pos[g] = p;
        cursor[g] = p;
    }
}

__global__ __launch_bounds__(256) void k_bin(const int* __restrict__ dst, const int* __restrict__ src,
                                             const int* __restrict__ etypes,
                                             int* __restrict__ cursor, int* __restrict__ packed) {
    int e = blockIdx.x * 256 + threadIdx.x;
    if (e < N_EDGES) {
        int slot = atomicAdd(&cursor[dst[e]], 1);
        packed[slot] = src[e] | (etypes[e] << 16);  // src < 65536, et < 4
    }
}

// ---------------------------------------------------------------------------
// Per-node aggregation, one wave per node, bf16-packed gathers (192B/edge),
// 4-deep unrolled for ILP. Scat[d][et*96+k] bf16; counts[d][et] f32.
// ---------------------------------------------------------------------------
__global__ __launch_bounds__(64) void k_agg(const unsigned* __restrict__ featb,
                                            const int* __restrict__ pos, const int* __restrict__ deg,
                                            const int* __restrict__ packed,
                                            unsigned* __restrict__ Scat_u32,
                                            float* __restrict__ counts) {
    const int d = blockIdx.x;
    const int lane = threadIdx.x;
    const bool act = lane < 48;
    const int start = pos[d], cnt = deg[d];

    float2 a0 = {0.f, 0.f}, a1 = {0.f, 0.f}, a2 = {0.f, 0.f}, a3 = {0.f, 0.f};
    int c0 = 0, c1 = 0, c2 = 0, c3 = 0;

#define UNPACK(u, v)                                    \
    { v.x = __uint_as_float((u) << 16);                 \
      v.y = __uint_as_float((u) & 0xFFFF0000u); }

    int i = 0;
    for (; i + 4 <= cnt; i += 4) {
        int p0 = packed[start + i + 0];
        int p1 = packed[start + i + 1];
        int p2 = packed[start + i + 2];
        int p3 = packed[start + i + 3];
        unsigned u0 = act ? featb[(size_t)(p0 & 0xFFFF) * 48 + lane] : 0u;
        unsigned u1 = act ? featb[(size_t)(p1 & 0xFFFF) * 48 + lane] : 0u;
        unsigned u2 = act ? featb[(size_t)(p2 & 0xFFFF) * 48 + lane] : 0u;
        unsigned u3 = act ? featb[(size_t)(p3 & 0xFFFF) * 48 + lane] : 0u;
        int e0 = p0 >> 16, e1 = p1 >> 16, e2 = p2 >> 16, e3 = p3 >> 16;
        float2 v0, v1, v2, v3;
        UNPACK(u0, v0); UNPACK(u1, v1); UNPACK(u2, v2); UNPACK(u3, v3);
        if (e0 == 0) { a0.x += v0.x; a0.y += v0.y; ++c0; }
        else if (e0 == 1) { a1.x += v0.x; a1.y += v0.y; ++c1; }
        else if (e0 == 2) { a2.x += v0.x; a2.y += v0.y; ++c2; }
        else              { a3.x += v0.x; a3.y += v0.y; ++c3; }
        if (e1 == 0) { a0.x += v1.x; a0.y += v1.y; ++c0; }
        else if (e1 == 1) { a1.x += v1.x; a1.y += v1.y; ++c1; }
        else if (e1 == 2) { a2.x += v1.x; a2.y += v1.y; ++c2; }
        else              { a3.x += v1.x; a3.y += v1.y; ++c3; }
        if (e2 == 0) { a0.x += v2.x; a0.y += v2.y; ++c0; }
        else if (e2 == 1) { a1.x += v2.x; a1.y += v2.y; ++c1; }
        else if (e2 == 2) { a2.x += v2.x; a2.y += v2.y; ++c2; }
        else              { a3.x += v2.x; a3.y += v2.y; ++c3; }
        if (e3 == 0) { a0.x += v3.x; a0.y += v3.y; ++c0; }
        else if (e3 == 1) { a1.x += v3.x; a1.y += v3.y; ++c1; }
        else if (e3 == 2) { a2.x += v3.x; a2.y += v3.y; ++c2; }
        else              { a3.x += v3.x; a3.y += v3.y; ++c3; }
    }
    for (; i < cnt; ++i) {
        int p = packed[start + i];
        unsigned u = act ? featb[(size_t)(p & 0xFFFF) * 48 + lane] : 0u;
        int e = p >> 16;
        float2 v;
        UNPACK(u, v);
        if (e == 0) { a0.x += v.x; a0.y += v.y; ++c0; }
        else if (e == 1) { a1.x += v.x; a1.y += v.y; ++c1; }
        else if (e == 2) { a2.x += v.x; a2.y += v.y; ++c2; }
        else              { a3.x += v.x; a3.y += v.y; ++c3; }
    }
#undef UNPACK

    if (act) {
        size_t base = (size_t)d * (KCAT / 2) + lane;  // row stride 192 uints
        Scat_u32[base]       = pack2bf(a0.x, a0.y);
        Scat_u32[base + 48]  = pack2bf(a1.x, a1.y);
        Scat_u32[base + 96]  = pack2bf(a2.x, a2.y);
        Scat_u32[base + 144] = pack2bf(a3.x, a3.y);
    }
    if (lane < 4) counts[d * 4 + lane] = (float)(lane == 0 ? c0 : lane == 1 ? c1 : lane == 2 ? c2 : c3);
}

// ---------------------------------------------------------------------------
// MFMA GEMM: out[m][n] = sum_{k'<384} Scat[m][k'] * Wcat[n][k'] + bias
// Block 128x128, 4 waves (2x2), K-step 96 (== one etype per step).
// ---------------------------------------------------------------------------
#define LDT 104  // padded LDS row (bf16 elems)

__global__ __launch_bounds__(256) void k_gemm(const __hip_bfloat16* __restrict__ Scat,
                                              const float* __restrict__ W,
                                              const float* __restrict__ b,
                                              const float* __restrict__ counts,
                                              float* __restrict__ out) {
    __shared__ __align__(16) __hip_bfloat16 As[128][LDT];
    __shared__ __align__(16) __hip_bfloat16 Bs[128][LDT];
    const int m0 = blockIdx.x * 128;
    const int tid = threadIdx.x, lane = tid & 63, wave = tid >> 6;
    const int wm = wave >> 1, wn = wave & 1;

    f32x4 acc[4][4];
#pragma unroll
    for (int i = 0; i < 4; ++i)
#pragma unroll
        for (int jj = 0; jj < 4; ++jj) acc[i][jj] = (f32x4){0.f, 0.f, 0.f, 0.f};

    for (int ks = 0; ks < 4; ++ks) {  // ks == etype
#pragma unroll
        for (int it = 0; it < 6; ++it) {
            int idx = tid + it * 256;          // 0..1535
            int row = idx / 12, c8 = idx % 12;
            int gm = m0 + row;
            if (gm > N_NODES - 1) gm = N_NODES - 1;
            short8 v = *reinterpret_cast<const short8*>(&Scat[(size_t)gm * KCAT + ks * IN_FEATS + c8 * 8]);
            *reinterpret_cast<short8*>(&As[row][c8 * 8]) = v;
        }
#pragma unroll
        for (int it = 0; it < 12; ++it) {
            int idx = tid + it * 256;          // 0..3071
            int row = idx / 24, c4 = idx % 24;
            float4 v = *reinterpret_cast<const float4*>(&W[(size_t)(ks * OUT_FEATS + row) * OUT_FEATS + c4 * 4]);
            short4v sv;
            sv[0] = f2bf_bits(v.x); sv[1] = f2bf_bits(v.y);
            sv[2] = f2bf_bits(v.z); sv[3] = f2bf_bits(v.w);
            *reinterpret_cast<short4v*>(&Bs[row][c4 * 4]) = sv;
        }
        __syncthreads();
#pragma unroll
        for (int kk = 0; kk < 3; ++kk) {
            short8 af[4], bf[4];
#pragma unroll
            for (int mi = 0; mi < 4; ++mi)
                af[mi] = *reinterpret_cast<const short8*>(&As[wm * 64 + mi * 16 + (lane & 15)][kk * 32 + (lane >> 4) * 8]);
#pragma unroll
            for (int ni = 0; ni < 4; ++ni)
                bf[ni] = *reinterpret_cast<const short8*>(&Bs[wn * 64 + ni * 16 + (lane & 15)][kk * 32 + (lane >> 4) * 8]);
#pragma unroll
            for (int mi = 0; mi < 4; ++mi)
#pragma unroll
                for (int ni = 0; ni < 4; ++ni)
                    acc[mi][ni] = __builtin_amdgcn_mfma_f32_16x16x32_bf16(af[mi], bf[ni], acc[mi][ni], 0, 0, 0);
        }
        __syncthreads();
    }

#pragma unroll
    for (int mi = 0; mi < 4; ++mi) {
#pragma unroll
        for (int r = 0; r < 4; ++r) {
            int m = m0 + wm * 64 + mi * 16 + (lane >> 4) * 4 + r;
            if (m < N_NODES) {
                float4 c4 = *reinterpret_cast<const float4*>(&counts[m * 4]);
#pragma unroll
                for (int ni = 0; ni < 4; ++ni) {
                    int n = wn * 64 + ni * 16 + (lane & 15);
                    float bias = c4.x * b[n] + c4.y * b[OUT_FEATS + n] +
                                 c4.z * b[2 * OUT_FEATS + n] + c4.w * b[3 * OUT_FEATS + n];
                    out[(size_t)m * OUT_FEATS + n] = acc[mi][ni][r] + bias;
                }
            }
        }
    }
}

// ---------------------------------------------------------------------------
// Fallback (ws too small): direct per-(edge, j) dot product with atomics.
// ---------------------------------------------------------------------------
__global__ __launch_bounds__(256) void edge_direct(const float* __restrict__ feat,
                                                   const int* __restrict__ etypes,
                                                   const int* __restrict__ src,
                                                   const int* __restrict__ dst,
                                                   const float* __restrict__ W,
                                                   const float* __restrict__ b,
                                                   float* __restrict__ out) {
    int gid = blockIdx.x * 256 + threadIdx.x;
    int e = gid >> 7;
    int j = gid & 127;
    if (e >= N_EDGES) return;
    int et = etypes[e];
    int s = src[e];
    int d = dst[e];
    const float* f = feat + (size_t)s * IN_FEATS;
    const float* w = W + ((size_t)et * OUT_FEATS + j) * OUT_FEATS;
    float acc = b[et * OUT_FEATS + j];
    for (int k = 0; k < IN_FEATS; ++k) acc += f[k] * w[k];
    atomicAdd(&out[(size_t)d * OUT_FEATS + j], acc);
}

extern "C" void kernel_launch(void* const* d_in, const int* in_sizes, int n_in,
                              void* d_out, int out_size, void* d_ws, size_t ws_size,
                              hipStream_t stream) {
    const float* feat  = (const float*)d_in[0];
    const int*   etyps = (const int*)d_in[1];
    const int*   src   = (const int*)d_in[2];
    const int*   dst   = (const int*)d_in[3];
    const float* W     = (const float*)d_in[4];
    const float* b     = (const float*)d_in[5];
    float* out = (float*)d_out;

    const size_t off_scat   = 0;                                       // 38,400,000
    const size_t off_counts = off_scat + (size_t)N_NODES * KCAT * 2;
    const size_t off_deg    = off_counts + (size_t)N_NODES * 4 * 4;
    const size_t off_pos    = off_deg + (size_t)N_NODES * 4;
    const size_t off_cursor = off_pos + (size_t)N_NODES * 4;
    const size_t off_packed = off_cursor + (size_t)N_NODES * 4;
    const size_t off_bsum   = off_packed + (size_t)N_EDGES * 4;
    const size_t off_bscan  = off_bsum + 1024;
    const size_t off_scrap  = off_bscan + 1024;
    const size_t off_featb  = off_scrap + 1024;                        // 9,600,000
    const size_t need = off_featb + (size_t)N_NODES * 48 * 4;

    if (ws_size >= need) {
        char* ws = (char*)d_ws;
        __hip_bfloat16* Scat = (__hip_bfloat16*)(ws + off_scat);
        unsigned* Scat_u32 = (unsigned*)(ws + off_scat);
        float* counts = (float*)(ws + off_counts);
        int* deg    = (int*)(ws + off_deg);
        int* pos    = (int*)(ws + off_pos);
        int* cursor = (int*)(ws + off_cursor);
        int* packed = (int*)(ws + off_packed);
        int* bsum   = (int*)(ws + off_bsum);
        int* bscan  = (int*)(ws + off_bscan);
        int* scrap  = (int*)(ws + off_scrap);
        unsigned* featb = (unsigned*)(ws + off_featb);

        const int nScanBlocks = (N_NODES + 255) / 256;  // 196

        k_zero<<<nScanBlocks, 256, 0, stream>>>(deg);
        k_cvt<<<(N_NODES * 48 + 255) / 256, 256, 0, stream>>>((const float2*)feat, featb);
        k_hist<<<(N_EDGES + 255) / 256, 256, 0, stream>>>(dst, deg);
        k_scan1<<<nScanBlocks, 256, 0, stream>>>(deg, N_NODES, pos, bsum);
        k_scan1<<<1, 256, 0, stream>>>(bsum, nScanBlocks, bscan, scrap);
        k_scan3<<<nScanBlocks, 256, 0, stream>>>(pos, bscan, cursor, N_NODES);
        k_bin<<<(N_EDGES + 255) / 256, 256, 0, stream>>>(dst, src, etyps, cursor, packed);
        k_agg<<<N_NODES, 64, 0, stream>>>(featb, pos, deg, packed, Scat_u32, counts);
        k_gemm<<<(N_NODES + 127) / 128, 256, 0, stream>>>(Scat, W, b, counts, out);
    } else {
        hipMemsetAsync(d_out, 0, (size_t)out_size * sizeof(float), stream);
        int nthreads = N_EDGES * OUT_FEATS;
        edge_direct<<<nthreads / 256, 256, 0, stream>>>(feat, etyps, src, dst, W, b, out);
    }
}

// Round 5
// 100.210 us; speedup vs baseline: 1.2512x; 1.2512x over previous
//
#include <hip/hip_runtime.h>
#include <hip/hip_bf16.h>

#define N_NODES 50000
#define N_EDGES 500000
#define IN_FEATS 96
#define OUT_FEATS 128
#define N_ETYPES 4
#define KCAT (N_ETYPES * IN_FEATS)  // 384

typedef __attribute__((ext_vector_type(8))) short short8;
typedef __attribute__((ext_vector_type(4))) float f32x4;

static __device__ inline short f2bf_bits(float f) {
    __hip_bfloat16 h = __float2bfloat16(f);
    return *reinterpret_cast<short*>(&h);
}
static __device__ inline unsigned pack2bf(float lo, float hi) {
    unsigned l = (unsigned short)f2bf_bits(lo);
    unsigned h = (unsigned short)f2bf_bits(hi);
    return l | (h << 16);
}

// ---------------------------------------------------------------------------
// k_init: zero deg[] AND pre-convert W (f32 [4][128][128], first 96 cols) to
// bf16 Wb [4*128][96] (stored as u32 pairs). One launch, two jobs.
// ---------------------------------------------------------------------------
__global__ __launch_bounds__(256) void k_init(int* __restrict__ deg,
                                              const float* __restrict__ W,
                                              unsigned* __restrict__ Wb_u32) {
    int g = blockIdx.x * 256 + threadIdx.x;
    if (g < N_NODES) deg[g] = 0;
    if (g < 512 * 48) {  // 512 rows x 48 u32-pairs (96 bf16) per row
        int row = g / 48, pair = g % 48;
        float lo = W[(size_t)row * OUT_FEATS + pair * 2];
        float hi = W[(size_t)row * OUT_FEATS + pair * 2 + 1];
        Wb_u32[g] = pack2bf(lo, hi);
    }
}

// ---------------------------------------------------------------------------
// k_hist: degree histogram + per-edge rank (this edge's slot within its node)
// ---------------------------------------------------------------------------
__global__ __launch_bounds__(256) void k_hist(const int* __restrict__ dst,
                                              int* __restrict__ deg,
                                              int* __restrict__ rank) {
    int e = blockIdx.x * 256 + threadIdx.x;
    if (e < N_EDGES) rank[e] = atomicAdd(&deg[dst[e]], 1);
}

__global__ __launch_bounds__(256) void k_scan1(const int* __restrict__ in, int n,
                                               int* __restrict__ out, int* __restrict__ bsum) {
    int g = blockIdx.x * 256 + threadIdx.x;
    int lane = threadIdx.x & 63, wave = threadIdx.x >> 6;
    int v = (g < n) ? in[g] : 0;
    int orig = v;
    for (int off = 1; off < 64; off <<= 1) {
        int u = __shfl_up(v, off);
        if (lane >= off) v += u;
    }
    __shared__ int wsum[4];
    if (lane == 63) wsum[wave] = v;
    __syncthreads();
    if (threadIdx.x == 0) {
        int s = 0;
        for (int w = 0; w < 4; ++w) { int t = wsum[w]; wsum[w] = s; s += t; }
        bsum[blockIdx.x] = s;
    }
    __syncthreads();
    int excl = v - orig + wsum[wave];
    if (g < n) out[g] = excl;
}

__global__ __launch_bounds__(256) void k_scan3(int* __restrict__ pos, const int* __restrict__ bscan, int n) {
    int g = blockIdx.x * 256 + threadIdx.x;
    if (g < n) pos[g] += bscan[blockIdx.x];
}

// k_bin: atomic-free scatter using precomputed rank
__global__ __launch_bounds__(256) void k_bin(const int* __restrict__ dst, const int* __restrict__ src,
                                             const int* __restrict__ etypes,
                                             const int* __restrict__ pos, const int* __restrict__ rank,
                                             int* __restrict__ packed) {
    int e = blockIdx.x * 256 + threadIdx.x;
    if (e < N_EDGES) {
        int slot = pos[dst[e]] + rank[e];
        packed[slot] = src[e] | (etypes[e] << 16);  // src < 65536, et < 4
    }
}

// ---------------------------------------------------------------------------
// Per-node aggregation, one wave per node, f32 float2 gathers, 4-deep
// unrolled for ILP. Scat[d][et*96+k] bf16; counts[d][et] f32. No atomics.
// ---------------------------------------------------------------------------
__global__ __launch_bounds__(64) void k_agg(const float2* __restrict__ feat2,
                                            const int* __restrict__ pos, const int* __restrict__ deg,
                                            const int* __restrict__ packed,
                                            unsigned* __restrict__ Scat_u32,
                                            float* __restrict__ counts) {
    const int d = blockIdx.x;
    const int lane = threadIdx.x;
    const bool act = lane < 48;
    const int start = pos[d], cnt = deg[d];

    float2 a0 = {0.f, 0.f}, a1 = {0.f, 0.f}, a2 = {0.f, 0.f}, a3 = {0.f, 0.f};
    int c0 = 0, c1 = 0, c2 = 0, c3 = 0;
    const float2 zero = {0.f, 0.f};

    int i = 0;
    for (; i + 4 <= cnt; i += 4) {
        int p0 = packed[start + i + 0];
        int p1 = packed[start + i + 1];
        int p2 = packed[start + i + 2];
        int p3 = packed[start + i + 3];
        float2 v0 = act ? feat2[(size_t)(p0 & 0xFFFF) * 48 + lane] : zero;
        float2 v1 = act ? feat2[(size_t)(p1 & 0xFFFF) * 48 + lane] : zero;
        float2 v2 = act ? feat2[(size_t)(p2 & 0xFFFF) * 48 + lane] : zero;
        float2 v3 = act ? feat2[(size_t)(p3 & 0xFFFF) * 48 + lane] : zero;
        int e0 = p0 >> 16, e1 = p1 >> 16, e2 = p2 >> 16, e3 = p3 >> 16;
        if (e0 == 0) { a0.x += v0.x; a0.y += v0.y; ++c0; }
        else if (e0 == 1) { a1.x += v0.x; a1.y += v0.y; ++c1; }
        else if (e0 == 2) { a2.x += v0.x; a2.y += v0.y; ++c2; }
        else              { a3.x += v0.x; a3.y += v0.y; ++c3; }
        if (e1 == 0) { a0.x += v1.x; a0.y += v1.y; ++c0; }
        else if (e1 == 1) { a1.x += v1.x; a1.y += v1.y; ++c1; }
        else if (e1 == 2) { a2.x += v1.x; a2.y += v1.y; ++c2; }
        else              { a3.x += v1.x; a3.y += v1.y; ++c3; }
        if (e2 == 0) { a0.x += v2.x; a0.y += v2.y; ++c0; }
        else if (e2 == 1) { a1.x += v2.x; a1.y += v2.y; ++c1; }
        else if (e2 == 2) { a2.x += v2.x; a2.y += v2.y; ++c2; }
        else              { a3.x += v2.x; a3.y += v2.y; ++c3; }
        if (e3 == 0) { a0.x += v3.x; a0.y += v3.y; ++c0; }
        else if (e3 == 1) { a1.x += v3.x; a1.y += v3.y; ++c1; }
        else if (e3 == 2) { a2.x += v3.x; a2.y += v3.y; ++c2; }
        else              { a3.x += v3.x; a3.y += v3.y; ++c3; }
    }
    for (; i < cnt; ++i) {
        int p = packed[start + i];
        float2 v = act ? feat2[(size_t)(p & 0xFFFF) * 48 + lane] : zero;
        int e = p >> 16;
        if (e == 0) { a0.x += v.x; a0.y += v.y; ++c0; }
        else if (e == 1) { a1.x += v.x; a1.y += v.y; ++c1; }
        else if (e == 2) { a2.x += v.x; a2.y += v.y; ++c2; }
        else              { a3.x += v.x; a3.y += v.y; ++c3; }
    }

    if (act) {
        size_t base = (size_t)d * (KCAT / 2) + lane;  // row stride 192 uints
        Scat_u32[base]       = pack2bf(a0.x, a0.y);
        Scat_u32[base + 48]  = pack2bf(a1.x, a1.y);
        Scat_u32[base + 96]  = pack2bf(a2.x, a2.y);
        Scat_u32[base + 144] = pack2bf(a3.x, a3.y);
    }
    if (lane < 4) counts[d * 4 + lane] = (float)(lane == 0 ? c0 : lane == 1 ? c1 : lane == 2 ? c2 : c3);
}

// ---------------------------------------------------------------------------
// MFMA GEMM: out[m][n] = sum_{k'<384} Scat[m][k'] * Wb[n][k'] + bias
// Block 128x128, 4 waves (2x2), K-step 96 (== one etype per step).
// B-stage is now a pure short8 copy from precomputed bf16 Wb.
// ---------------------------------------------------------------------------
#define LDT 104  // padded LDS row (bf16 elems): 208B stride, conflict-free frag reads

__global__ __launch_bounds__(256) void k_gemm(const __hip_bfloat16* __restrict__ Scat,
                                              const short* __restrict__ Wb,
                                              const float* __restrict__ b,
                                              const float* __restrict__ counts,
                                              float* __restrict__ out) {
    __shared__ __align__(16) __hip_bfloat16 As[128][LDT];
    __shared__ __align__(16) __hip_bfloat16 Bs[128][LDT];
    const int m0 = blockIdx.x * 128;
    const int tid = threadIdx.x, lane = tid & 63, wave = tid >> 6;
    const int wm = wave >> 1, wn = wave & 1;

    f32x4 acc[4][4];
#pragma unroll
    for (int i = 0; i < 4; ++i)
#pragma unroll
        for (int jj = 0; jj < 4; ++jj) acc[i][jj] = (f32x4){0.f, 0.f, 0.f, 0.f};

    for (int ks = 0; ks < 4; ++ks) {  // ks == etype
#pragma unroll
        for (int it = 0; it < 6; ++it) {
            int idx = tid + it * 256;          // 0..1535
            int row = idx / 12, c8 = idx % 12;
            int gm = m0 + row;
            if (gm > N_NODES - 1) gm = N_NODES - 1;
            short8 v = *reinterpret_cast<const short8*>(&Scat[(size_t)gm * KCAT + ks * IN_FEATS + c8 * 8]);
            *reinterpret_cast<short8*>(&As[row][c8 * 8]) = v;
        }
#pragma unroll
        for (int it = 0; it < 6; ++it) {
            int idx = tid + it * 256;          // 0..1535
            int row = idx / 12, c8 = idx % 12;
            short8 v = *reinterpret_cast<const short8*>(&Wb[((size_t)ks * OUT_FEATS + row) * IN_FEATS + c8 * 8]);
            *reinterpret_cast<short8*>(&Bs[row][c8 * 8]) = v;
        }
        __syncthreads();
#pragma unroll
        for (int kk = 0; kk < 3; ++kk) {
            short8 af[4], bf[4];
#pragma unroll
            for (int mi = 0; mi < 4; ++mi)
                af[mi] = *reinterpret_cast<const short8*>(&As[wm * 64 + mi * 16 + (lane & 15)][kk * 32 + (lane >> 4) * 8]);
#pragma unroll
            for (int ni = 0; ni < 4; ++ni)
                bf[ni] = *reinterpret_cast<const short8*>(&Bs[wn * 64 + ni * 16 + (lane & 15)][kk * 32 + (lane >> 4) * 8]);
#pragma unroll
            for (int mi = 0; mi < 4; ++mi)
#pragma unroll
                for (int ni = 0; ni < 4; ++ni)
                    acc[mi][ni] = __builtin_amdgcn_mfma_f32_16x16x32_bf16(af[mi], bf[ni], acc[mi][ni], 0, 0, 0);
        }
        __syncthreads();
    }

#pragma unroll
    for (int mi = 0; mi < 4; ++mi) {
#pragma unroll
        for (int r = 0; r < 4; ++r) {
            int m = m0 + wm * 64 + mi * 16 + (lane >> 4) * 4 + r;
            if (m < N_NODES) {
                float4 c4 = *reinterpret_cast<const float4*>(&counts[m * 4]);
#pragma unroll
                for (int ni = 0; ni < 4; ++ni) {
                    int n = wn * 64 + ni * 16 + (lane & 15);
                    float bias = c4.x * b[n] + c4.y * b[OUT_FEATS + n] +
                                 c4.z * b[2 * OUT_FEATS + n] + c4.w * b[3 * OUT_FEATS + n];
                    out[(size_t)m * OUT_FEATS + n] = acc[mi][ni][r] + bias;
                }
            }
        }
    }
}

// ---------------------------------------------------------------------------
// Fallback (ws too small): direct per-(edge, j) dot product with atomics.
// ---------------------------------------------------------------------------
__global__ __launch_bounds__(256) void edge_direct(const float* __restrict__ feat,
                                                   const int* __restrict__ etypes,
                                                   const int* __restrict__ src,
                                                   const int* __restrict__ dst,
                                                   const float* __restrict__ W,
                                                   const float* __restrict__ b,
                                                   float* __restrict__ out) {
    int gid = blockIdx.x * 256 + threadIdx.x;
    int e = gid >> 7;
    int j = gid & 127;
    if (e >= N_EDGES) return;
    int et = etypes[e];
    int s = src[e];
    int d = dst[e];
    const float* f = feat + (size_t)s * IN_FEATS;
    const float* w = W + ((size_t)et * OUT_FEATS + j) * OUT_FEATS;
    float acc = b[et * OUT_FEATS + j];
    for (int k = 0; k < IN_FEATS; ++k) acc += f[k] * w[k];
    atomicAdd(&out[(size_t)d * OUT_FEATS + j], acc);
}

extern "C" void kernel_launch(void* const* d_in, const int* in_sizes, int n_in,
                              void* d_out, int out_size, void* d_ws, size_t ws_size,
                              hipStream_t stream) {
    const float* feat  = (const float*)d_in[0];
    const int*   etyps = (const int*)d_in[1];
    const int*   src   = (const int*)d_in[2];
    const int*   dst   = (const int*)d_in[3];
    const float* W     = (const float*)d_in[4];
    const float* b     = (const float*)d_in[5];
    float* out = (float*)d_out;

    const size_t off_scat   = 0;                                        // 38,400,000
    const size_t off_counts = off_scat + (size_t)N_NODES * KCAT * 2;    // +800,000
    const size_t off_deg    = off_counts + (size_t)N_NODES * 4 * 4;     // +200,000
    const size_t off_pos    = off_deg + (size_t)N_NODES * 4;            // +200,000
    const size_t off_rank   = off_pos + (size_t)N_NODES * 4;            // +2,000,000
    const size_t off_packed = off_rank + (size_t)N_EDGES * 4;           // +2,000,000
    const size_t off_bsum   = off_packed + (size_t)N_EDGES * 4;
    const size_t off_bscan  = off_bsum + 1024;
    const size_t off_scrap  = off_bscan + 1024;
    const size_t off_wb     = off_scrap + 1024;                         // +98,304
    const size_t need = off_wb + (size_t)512 * IN_FEATS * 2;

    if (ws_size >= need) {
        char* ws = (char*)d_ws;
        __hip_bfloat16* Scat = (__hip_bfloat16*)(ws + off_scat);
        unsigned* Scat_u32 = (unsigned*)(ws + off_scat);
        float* counts = (float*)(ws + off_counts);
        int* deg    = (int*)(ws + off_deg);
        int* pos    = (int*)(ws + off_pos);
        int* rank   = (int*)(ws + off_rank);
        int* packed = (int*)(ws + off_packed);
        int* bsum   = (int*)(ws + off_bsum);
        int* bscan  = (int*)(ws + off_bscan);
        int* scrap  = (int*)(ws + off_scrap);
        unsigned* Wb_u32 = (unsigned*)(ws + off_wb);
        short* Wb = (short*)(ws + off_wb);

        const int nScanBlocks = (N_NODES + 255) / 256;  // 196
        const int nEdgeBlocks = (N_EDGES + 255) / 256;  // 1954

        k_init<<<nScanBlocks, 256, 0, stream>>>(deg, W, Wb_u32);
        k_hist<<<nEdgeBlocks, 256, 0, stream>>>(dst, deg, rank);
        k_scan1<<<nScanBlocks, 256, 0, stream>>>(deg, N_NODES, pos, bsum);
        k_scan1<<<1, 256, 0, stream>>>(bsum, nScanBlocks, bscan, scrap);
        k_scan3<<<nScanBlocks, 256, 0, stream>>>(pos, bscan, N_NODES);
        k_bin<<<nEdgeBlocks, 256, 0, stream>>>(dst, src, etyps, pos, rank, packed);
        k_agg<<<N_NODES, 64, 0, stream>>>((const float2*)feat, pos, deg, packed, Scat_u32, counts);
        k_gemm<<<(N_NODES + 127) / 128, 256, 0, stream>>>(Scat, Wb, b, counts, out);
    } else {
        hipMemsetAsync(d_out, 0, (size_t)out_size * sizeof(float), stream);
        int nthreads = N_EDGES * OUT_FEATS;
        edge_direct<<<nthreads / 256, 256, 0, stream>>>(feat, etyps, src, dst, W, b, out);
    }
}